// Round 1
// baseline (244.774 us; speedup 1.0000x reference)
//
#include <hip/hip_runtime.h>

#define N_TOK   524288
#define KC      256
#define D       32
#define EPSF    1e-6f
#define TPT     64                 // tokens per tile
#define NTILES  (N_TOK / TPT)      // 8192
#define NBLK    768                // 3 blocks/CU x 256 CUs, all resident
#define BLKT    256

// ---------------- main kernel: argmin + rotation + per-block histogram ----------------
__global__ __launch_bounds__(BLKT) void vq_main(
    const float* __restrict__ x, const float* __restrict__ cb,
    float* __restrict__ out_rot, float* __restrict__ out_idx,
    float* __restrict__ ws_hist, float* __restrict__ out_cnt, int use_ws)
{
    __shared__ float ct[D][KC];       // codebook transposed (32 KB)
    __shared__ float c2s[KC];         // ||c||^2, numpy pairwise order (1 KB)
    __shared__ float xt[2][D][TPT];   // x tile transposed, double-buffered (16 KB)
                                      // col-swizzled: (k,tok) stored at col tok^((k>>3)<<4)
    __shared__ float x2s[2][TPT];     // ||x||^2 per token (512 B)
    __shared__ float hist[KC];        // per-block histogram (1 KB)
    // total 51712 B -> 3 blocks/CU (LDS-limited, same as before)

    const int tid  = threadIdx.x;
    const int lane = tid & 63;

    // ---- stage codebook transposed + c2 (numpy pairwise), zero hist ----
    {
#pragma clang fp contract(off)
        const float4* cb4 = (const float4*)(cb + (size_t)tid * D);
        float4 r[8];
#pragma unroll
        for (int j = 0; j < 8; j++) r[j] = cb4[j];
        float t[32];
#pragma unroll
        for (int j = 0; j < 8; j++) {
            t[4 * j + 0] = r[j].x * r[j].x;
            t[4 * j + 1] = r[j].y * r[j].y;
            t[4 * j + 2] = r[j].z * r[j].z;
            t[4 * j + 3] = r[j].w * r[j].w;
        }
        float pr[8];
#pragma unroll
        for (int j = 0; j < 8; j++)
            pr[j] = ((t[j] + t[j + 8]) + t[j + 16]) + t[j + 24];
        c2s[tid] = ((pr[0] + pr[1]) + (pr[2] + pr[3])) + ((pr[4] + pr[5]) + (pr[6] + pr[7]));
#pragma unroll
        for (int j = 0; j < 8; j++) {
            ct[4 * j + 0][tid] = r[j].x;
            ct[4 * j + 1][tid] = r[j].y;
            ct[4 * j + 2][tid] = r[j].z;
            ct[4 * j + 3][tid] = r[j].w;
        }
        hist[tid] = 0.f;
    }

    const int tt   = tid >> 4;              // token group 0..15 (4 tokens each)
    const int tc   = tid & 15;              // code  group 0..15 (4x4 codes, stride 64)
    const int tok  = tid >> 2;              // staging/epilogue token (block-local)
    const int sub  = tid & 3;               // dim slice 0..3 (8 dims each)
    const int colw = tok ^ (sub << 4);      // swizzled write column: 2-way banks, not 4-way

    // stage one tile (held in regs) into xt[buf]; x2 computed IN REGISTERS with the
    // exact numpy pairwise order: pr[j] = ((t[j]+t[j+8])+t[j+16])+t[j+24], t split
    // across the 4 sub-lanes of a token. fp add is commutative bitwise, chain order kept.
    auto stage = [&](int buf, float4 a, float4 b) {
#pragma clang fp contract(off)
        float xs[8] = {a.x, a.y, a.z, a.w, b.x, b.y, b.z, b.w};
        const int k0 = sub * 8;
#pragma unroll
        for (int j = 0; j < 8; j++) xt[buf][k0 + j][colw] = xs[j];
        float sq[8];
#pragma unroll
        for (int j = 0; j < 8; j++) sq[j] = xs[j] * xs[j];
        const int base = lane & ~3;
        float pr[8];
#pragma unroll
        for (int j = 0; j < 8; j++) {
            float t01 = sq[j] + __shfl_xor(sq[j], 1, 64);   // on sub0: t[j]+t[j+8]
            float s2  = __shfl(sq[j], base + 2, 64);        // t[j+16]
            float s3  = __shfl(sq[j], base + 3, 64);        // t[j+24]
            pr[j] = (t01 + s2) + s3;
        }
        float v = ((pr[0] + pr[1]) + (pr[2] + pr[3])) + ((pr[4] + pr[5]) + (pr[6] + pr[7]));
        if (sub == 0) x2s[buf][tok] = v;
    };

    // ---- prologue: load + stage tile0 ----
    float4 aC, bC;
    {
        const float4* xg = (const float4*)(x + (size_t)blockIdx.x * TPT * D + (size_t)tid * 8);
        aC = xg[0]; bC = xg[1];
    }
    stage(0, aC, bC);
    __syncthreads();

    int cur = 0;
    for (int tile = blockIdx.x; tile < NTILES; tile += gridDim.x) {
        const int nt = tile + gridDim.x;
        const bool hasN = (nt < NTILES);          // block-uniform
        float4 aN = aC, bN = bC;
        if (hasN) {                                // issue next-tile loads early; first use
            const float4* xg = (const float4*)(x + (size_t)nt * TPT * D + (size_t)tid * 8);
            aN = xg[0]; bN = xg[1];                // is in stage() after the score loop
        }

        // ---- scores: 4 tokens x 16 codes per thread, single fused k-loop ----
        float x4[4];
#pragma unroll
        for (int i = 0; i < 4; i++) x4[i] = x2s[cur][tt * 4 + i];

        float acc[4][16];
#pragma unroll
        for (int i = 0; i < 4; i++)
#pragma unroll
            for (int j = 0; j < 16; j++) acc[i][j] = 0.f;

        // sequential fused-FMA over k ascending == same chain per code as before.
        // ct reads at tc*4 + {0,64,128,192}: stride-4 banks -> 2-way (free).
#pragma unroll 4
        for (int k = 0; k < D; k++) {
            const int xcol = (tt * 4) ^ ((k >> 3) << 4);   // undo staging swizzle
            const float4 xv = *(const float4*)&xt[cur][k][xcol];
            const float4 v0 = *(const float4*)&ct[k][tc * 4];
            const float4 v1 = *(const float4*)&ct[k][64 + tc * 4];
            const float4 v2 = *(const float4*)&ct[k][128 + tc * 4];
            const float4 v3 = *(const float4*)&ct[k][192 + tc * 4];
            const float xs[4]  = {xv.x, xv.y, xv.z, xv.w};
            const float cs[16] = {v0.x, v0.y, v0.z, v0.w, v1.x, v1.y, v1.z, v1.w,
                                  v2.x, v2.y, v2.z, v2.w, v3.x, v3.y, v3.z, v3.w};
#pragma unroll
            for (int i = 0; i < 4; i++)
#pragma unroll
                for (int j = 0; j < 16; j++)
                    acc[i][j] = __builtin_fmaf(xs[i], cs[j], acc[i][j]);
        }

        // d2 = fl(fl(x2 - 2*xc) + c2) — same op order; per-thread codes ascending,
        // strict < keeps lowest index among exact ties.
        float bestv[4] = {3.4e38f, 3.4e38f, 3.4e38f, 3.4e38f};
        int   besti[4] = {0x7fffffff, 0x7fffffff, 0x7fffffff, 0x7fffffff};
#pragma unroll
        for (int j = 0; j < 16; j++) {
            const int code = (j >> 2) * 64 + tc * 4 + (j & 3);
            const float c2v = c2s[code];
#pragma unroll
            for (int i = 0; i < 4; i++) {
                float t2 = x4[i] - 2.0f * acc[i][j];
                float s  = t2 + c2v;
                if (s < bestv[i]) { bestv[i] = s; besti[i] = code; }
            }
        }

        // cross-lane argmin over the 16 code-threads; index tie-break = global first-min
#pragma unroll
        for (int m = 1; m < 16; m <<= 1) {
#pragma unroll
            for (int i = 0; i < 4; i++) {
                float ov = __shfl_xor(bestv[i], m, 64);
                int   oi = __shfl_xor(besti[i], m, 64);
                if (ov < bestv[i] || (ov == bestv[i] && oi < besti[i])) {
                    bestv[i] = ov; besti[i] = oi;
                }
            }
        }

        // broadcast winner to epilogue lanes intra-wave (no LDS, no barrier):
        // epilogue token t=lane>>2 lives in score group tt=lane>>4 -> src lane = lane&48
        const int src = lane & 48;
        const int b0 = __shfl(besti[0], src, 64);
        const int b1 = __shfl(besti[1], src, 64);
        const int b2 = __shfl(besti[2], src, 64);
        const int b3 = __shfl(besti[3], src, 64);
        const int ii = (lane >> 2) & 3;
        const int bi = (ii == 0) ? b0 : (ii == 1) ? b1 : (ii == 2) ? b2 : b3;

        // ---- rotation epilogue: x slice already in regs (same thread staged it) ----
        {
            const size_t gtok = (size_t)tile * TPT + tok;
            const float4* cg = (const float4*)(cb + (size_t)bi * D + sub * 8);
            float4 ca = cg[0], cbv = cg[1];

            float xs8[8] = {aC.x, aC.y, aC.z, aC.w, bC.x, bC.y, bC.z, bC.w};
            float cs8[8] = {ca.x, ca.y, ca.z, ca.w, cbv.x, cbv.y, cbv.z, cbv.w};

            float px2 = 0.f, pc2 = 0.f;
#pragma unroll
            for (int j = 0; j < 8; j++) { px2 = fmaf(xs8[j], xs8[j], px2); pc2 = fmaf(cs8[j], cs8[j], pc2); }
            float x2 = px2 + __shfl_xor(px2, 1, 64); x2 += __shfl_xor(x2, 2, 64);
            float c2 = pc2 + __shfl_xor(pc2, 1, 64); c2 += __shfl_xor(c2, 2, 64);
            const float inx = 1.f / fmaxf(sqrtf(x2), EPSF);
            const float inc = 1.f / fmaxf(sqrtf(c2), EPSF);

            float us8[8], qs8[8], ws8[8];
            float pw2 = 0.f;
#pragma unroll
            for (int j = 0; j < 8; j++) {
                us8[j] = xs8[j] * inx;
                qs8[j] = cs8[j] * inc;
                ws8[j] = us8[j] + qs8[j];
                pw2 = fmaf(ws8[j], ws8[j], pw2);
            }
            float w2 = pw2 + __shfl_xor(pw2, 1, 64); w2 += __shfl_xor(w2, 2, 64);
            const float inw = 1.f / fmaxf(sqrtf(w2), EPSF);

            float pew = 0.f, peu = 0.f;
#pragma unroll
            for (int j = 0; j < 8; j++) {
                ws8[j] *= inw;
                pew = fmaf(xs8[j], ws8[j], pew);
                peu = fmaf(xs8[j], us8[j], peu);
            }
            float ew = pew + __shfl_xor(pew, 1, 64); ew += __shfl_xor(ew, 2, 64);
            float eu = peu + __shfl_xor(peu, 1, 64); eu += __shfl_xor(eu, 2, 64);

            float ro[8];
#pragma unroll
            for (int j = 0; j < 8; j++)
                ro[j] = xs8[j] - 2.f * ew * ws8[j] + 2.f * eu * qs8[j];

            float4* og = (float4*)(out_rot + gtok * D + sub * 8);
            og[0] = make_float4(ro[0], ro[1], ro[2], ro[3]);
            og[1] = make_float4(ro[4], ro[5], ro[6], ro[7]);

            if (sub == 0) {
                out_idx[gtok] = (float)bi;
                atomicAdd(&hist[bi], 1.f);
            }
        }

        // stage next tile into the other buffer; ONE barrier per tile.
        // buf written here was last read one iteration ago (before that barrier) -> safe.
        if (hasN) stage(cur ^ 1, aN, bN);
        __syncthreads();
        aC = aN; bC = bN; cur ^= 1;
    }

    // ---- flush per-block histogram (last-iteration atomics precede the loop barrier) ----
    if (use_ws) ws_hist[(size_t)blockIdx.x * KC + tid] = hist[tid];
    else        atomicAdd(&out_cnt[tid], hist[tid]);
}

// ---------------- tiny reduce: 768 block-partials -> 256 counts ----------------
__global__ __launch_bounds__(256) void vq_reduce(const float* __restrict__ ws,
                                                 float* __restrict__ out_cnt)
{
    const int c = blockIdx.x * 8 + (threadIdx.x >> 5);  // code
    const int l = threadIdx.x & 31;                     // lane within code-group
    float s = 0.f;
    for (int b = l; b < NBLK; b += 32) s += ws[(size_t)b * KC + c];
#pragma unroll
    for (int m = 1; m < 32; m <<= 1) s += __shfl_xor(s, m, 64);
    if (l == 0) out_cnt[c] = s;
}

extern "C" void kernel_launch(void* const* d_in, const int* in_sizes, int n_in,
                              void* d_out, int out_size, void* d_ws, size_t ws_size,
                              hipStream_t stream)
{
    const float* x  = (const float*)d_in[0];
    const float* cb = (const float*)d_in[1];
    float* out      = (float*)d_out;
    float* out_rot  = out;                                   // [524288*32]
    float* out_idx  = out + (size_t)N_TOK * D;               // [524288] (indices as float)
    float* out_cnt  = out_idx + N_TOK;                       // [256]

    const size_t ws_need = (size_t)NBLK * KC * sizeof(float);
    const int use_ws = (ws_size >= ws_need) ? 1 : 0;
    if (!use_ws) hipMemsetAsync(out_cnt, 0, KC * sizeof(float), stream);

    vq_main<<<NBLK, BLKT, 0, stream>>>(x, cb, out_rot, out_idx,
                                       (float*)d_ws, out_cnt, use_ws);
    if (use_ws) vq_reduce<<<32, 256, 0, stream>>>((const float*)d_ws, out_cnt);
}